// Round 14
// baseline (2329.988 us; speedup 1.0000x reference)
//
#include <hip/hip_runtime.h>
#include <hip/hip_cooperative_groups.h>
#include <math.h>

namespace cg = cooperative_groups;

#define T_SEQ 12
// B=1024, NG=32, G=32, E=64, H=128, PP=512, BOT=1024, MLPD=1024

typedef __bf16 bf16x8 __attribute__((ext_vector_type(8)));
typedef float f32x4 __attribute__((ext_vector_type(4)));
typedef unsigned short u16x8 __attribute__((ext_vector_type(8)));

static __device__ __forceinline__ unsigned short bf16bits(float x) {
  return __builtin_bit_cast(unsigned short, (__bf16)x);
}

// Workspace layout (float offsets)
enum : int {
  OFF_LP    = 0,        // [1024,2]
  OFF_DIN   = 2048,     // [1024,64]
  OFF_C     = 198656,   // [1024,128]
  OFF_HDEC  = 329728,   // [1024,128]
  OFF_WC    = 460800,   // [2,512]
  OFF_BC    = 461824,   // [512]
  OFF_PW    = 462336,   // [1024,512]
  OFF_AA    = 986624,   // [1024,512]
  OFF_WP2T  = 1510912,  // [1024,512] bf16
  OFF_WM1T  = 1773056,  // [1024,1152] bf16
  OFF_HCATB = 2362880,  // [1024,1152] bf16 (h | pool)
  OFF_WM2TB = 2952704,  // [128,1024] bf16
  OFF_MIDB  = 3018240,  // [1024,1024] bf16
  OFF_WIHT  = 3542528,  // [64,512] f32 (W_ih^T)
  OFF_WHHT  = 3575296,  // [128,512] f32 (W_hh^T)
  OFF_WFRAG = 3640832   // [1024 frags][64 lanes][8] bf16 = 131072 floats
};                      // end 3771904 floats = 15.1 MB

// XOR swizzle: permute 16B slots within each 128B group by row&7
#define SWZP(byte, row) ((byte) ^ (((row) & 7) << 4))

__global__ __launch_bounds__(256) void k_setup(
    const float* __restrict__ last_pos, const float* __restrict__ lpr,
    const float* __restrict__ dh, const float* __restrict__ dc,
    const float* __restrict__ W_emb, const float* __restrict__ b_emb,
    float* __restrict__ lp, float* __restrict__ din,
    float* __restrict__ h_dec, float* __restrict__ c) {
  int idx = blockIdx.x * 256 + threadIdx.x;  // 0..131071
  if (idx < 2048) lp[idx] = last_pos[idx];
  h_dec[idx] = dh[idx];
  c[idx] = dc[idx];
  if (idx < 65536) {
    int b = idx >> 6, e = idx & 63;
    din[idx] = lpr[b*2] * W_emb[e] + lpr[b*2+1] * W_emb[64+e] + b_emb[e];
  }
}

__global__ __launch_bounds__(256) void k_wc(
    const float* __restrict__ W_sp, const float* __restrict__ b_sp,
    const float* __restrict__ W_pp1, const float* __restrict__ b_pp1,
    float* __restrict__ Wc, float* __restrict__ bc) {
  int n = blockIdx.x * 256 + threadIdx.x;
  if (n >= 512) return;
  float a0 = 0.f, a1 = 0.f, ab = 0.f;
#pragma unroll 8
  for (int k = 0; k < 64; k++) {
    float w = W_pp1[k*512 + n];
    a0 += W_sp[k] * w;
    a1 += W_sp[64+k] * w;
    ab += b_sp[k] * w;
  }
  Wc[n] = a0; Wc[512+n] = a1; bc[n] = ab + b_pp1[n];
}

// Transpose + convert fp32 [R][C] -> bf16 [C][R]
__global__ __launch_bounds__(256) void k_tcvt(
    const float* __restrict__ src, unsigned short* __restrict__ dst,
    int R, int C) {
  __shared__ float t[32][33];
  const int bx = blockIdx.x * 32, by = blockIdx.y * 32;
  const int tx = threadIdx.x & 31, ty = threadIdx.x >> 5;
#pragma unroll
  for (int i = 0; i < 32; i += 8) t[ty+i][tx] = src[(size_t)(by+ty+i)*C + bx+tx];
  __syncthreads();
#pragma unroll
  for (int i = 0; i < 32; i += 8)
    dst[(size_t)(bx+ty+i)*R + by+tx] = bf16bits(t[tx][ty+i]);
}

// Transpose fp32 [R][C] -> fp32 [C][R]
__global__ __launch_bounds__(256) void k_t32(
    const float* __restrict__ src, float* __restrict__ dst, int R, int C) {
  __shared__ float t[32][33];
  const int bx = blockIdx.x * 32, by = blockIdx.y * 32;
  const int tx = threadIdx.x & 31, ty = threadIdx.x >> 5;
#pragma unroll
  for (int i = 0; i < 32; i += 8) t[ty+i][tx] = src[(size_t)(by+ty+i)*C + bx+tx];
  __syncthreads();
#pragma unroll
  for (int i = 0; i < 32; i += 8)
    dst[(size_t)(bx+ty+i)*R + by+tx] = t[tx][ty+i];
}

// Re-arrange Wp2t [1024n][512k] into MFMA B-fragment order.
__global__ __launch_bounds__(256) void k_frag(
    const unsigned short* __restrict__ Wp2t, unsigned short* __restrict__ Wfrag) {
  const int tid = blockIdx.x * 256 + threadIdx.x;  // 0..65535
  const int fid = tid >> 6, l = tid & 63;
  const int nbb = fid >> 4, ks = fid & 15;
  u16x8 v = *(const u16x8*)(Wp2t + (size_t)(nbb*16 + (l & 15))*512 +
                            ks*32 + (l >> 4)*8);
  *(u16x8*)(Wfrag + (size_t)tid*8) = v;
}

// ===== MEGA cooperative kernel: the whole 12-step decoder loop =====
// Grid 256 blocks x 512 threads, 160KB LDS -> exactly 1 block/CU co-resident.
__global__ void __launch_bounds__(512)
k_mega(float* din, float* cst, float* h_dec, unsigned short* hcatB,
       float* lp, float* out,
       const float* Wiht, const float* b_ih,
       const float* Whht, const float* b_hh,
       const float* W_h2p, const float* b_h2p,
       const float* W_emb, const float* b_emb,
       const float* W1b, const float* Wc, const float* bc,
       float* PW, float* Aa,
       const unsigned short* Wfrag, const float* bp2,
       const unsigned short* Wm1t, const float* b_m1, unsigned short* midB,
       const unsigned short* Wm2tB, const float* b_m2) {
  cg::grid_group grid = cg::this_grid();
  __shared__ __align__(128) char smem[163840];
  const int bid = blockIdx.x;
  const int tid = threadIdx.x, lane = tid & 63, w = tid >> 6;
  const int l15 = lane & 15, lhi = lane >> 4;

  for (int t = 0; t < T_SEQ; t++) {
    // ---------- Phase 1: LSTM + pos + A-prep (4 rows/block) ----------
    {
      float* xh   = (float*)smem;       // 768
      float* gl   = xh + 768;           // 2048
      float* hbuf = gl + 2048;          // 512
      float* relS = hbuf + 512;         // 8
      float* curS = relS + 8;           // 8
      const int b0 = bid * 4;
      for (int i = tid; i < 768; i += 512) {
        int r = i / 192, k = i - r*192;
        xh[i] = (k < 64) ? din[(b0+r)*64 + k] : h_dec[(b0+r)*128 + k - 64];
      }
      __syncthreads();
      {
        const int n = tid;
        float bias = b_ih[n] + b_hh[n];
        float acc[4] = {bias, bias, bias, bias};
#pragma unroll 8
        for (int k = 0; k < 64; k++) {
          float wv = Wiht[k*512 + n];
#pragma unroll
          for (int r = 0; r < 4; r++) acc[r] += xh[r*192 + k] * wv;
        }
#pragma unroll 8
        for (int k = 0; k < 128; k++) {
          float wv = Whht[k*512 + n];
#pragma unroll
          for (int r = 0; r < 4; r++) acc[r] += xh[r*192 + 64 + k] * wv;
        }
#pragma unroll
        for (int r = 0; r < 4; r++) gl[r*512 + n] = acc[r];
      }
      __syncthreads();
      {
        int r = tid >> 7, hh = tid & 127;
        float ig = gl[r*512 + hh],       fg = gl[r*512 + 128 + hh];
        float gg = gl[r*512 + 256 + hh], og = gl[r*512 + 384 + hh];
        ig = 1.f/(1.f+expf(-ig)); fg = 1.f/(1.f+expf(-fg));
        gg = tanhf(gg);           og = 1.f/(1.f+expf(-og));
        int row = b0 + r;
        float c2 = fg * cst[row*128 + hh] + ig * gg;
        float h2 = og * tanhf(c2);
        cst[row*128 + hh] = c2;
        hbuf[r*128 + hh] = h2;
        hcatB[(size_t)row*1152 + hh] = bf16bits(h2);
      }
      __syncthreads();
      if (tid < 128) {
        int r = tid >> 5, col = (tid >> 4) & 1, l16 = tid & 15;
        float s = 0.f;
        for (int k = l16; k < 128; k += 16) s += hbuf[r*128 + k] * W_h2p[k*2 + col];
#pragma unroll
        for (int off = 8; off > 0; off >>= 1) s += __shfl_xor(s, off);
        if (l16 == 0) {
          float rel = s + b_h2p[col];
          float old = lp[(b0+r)*2 + col];
          relS[r*2 + col] = rel;
          curS[r*2 + col] = old + rel;
          lp[(b0+r)*2 + col] = old + rel;
          out[t*2048 + (b0+r)*2 + col] = rel;
        }
      }
      __syncthreads();
      if (tid < 256) {
        int r = tid >> 6, e = tid & 63;
        din[(b0+r)*64 + e] = relS[r*2]*W_emb[e] + relS[r*2+1]*W_emb[64+e] + b_emb[e];
      }
      {
        const int n = tid;
        float acc[4] = {0.f, 0.f, 0.f, 0.f};
#pragma unroll 4
        for (int k = 0; k < 128; k++) {
          float wv = W1b[k*512 + n];
#pragma unroll
          for (int r = 0; r < 4; r++) acc[r] += hbuf[r*128 + k] * wv;
        }
        float wc0 = Wc[n], wc1 = Wc[512+n], bcv = bc[n];
#pragma unroll
        for (int r = 0; r < 4; r++) {
          float pw = curS[r*2]*wc0 + curS[r*2+1]*wc1;
          PW[(size_t)(b0+r)*512 + n] = pw;
          Aa[(size_t)(b0+r)*512 + n] = acc[r] + pw + bcv;
        }
      }
    }
    grid.sync();

    // ---------- Phase 2: pool GEMM (pool8/R10 body) ----------
    {
      const int mt = (bid >> 3) & 7;
      const int g  = (bid & 7) + ((bid >> 6) << 3);
      const int wr = w >> 2, wcn = w & 3;
      char* As = smem;
      char* B0 = smem + 131072;
      char* B1 = smem + 131072 + 16384;
      {
        const int ke = lane * 8;
#pragma unroll 4
        for (int rr = 0; rr < 16; rr++) {
          const int r = rr * 8 + w;
          const int j = r & 31, ii = r >> 5;
          const float* aRow = Aa + (size_t)(g*32 + j)*512 + ke;
          const float* pRow = PW + (size_t)(g*32 + mt*4 + ii)*512 + ke;
          float4 a0 = *(const float4*)aRow;
          float4 a1 = *(const float4*)(aRow + 4);
          float4 p0 = *(const float4*)pRow;
          float4 p1 = *(const float4*)(pRow + 4);
          bf16x8 y;
          y[0] = (__bf16)fmaxf(a0.x - p0.x, 0.f);
          y[1] = (__bf16)fmaxf(a0.y - p0.y, 0.f);
          y[2] = (__bf16)fmaxf(a0.z - p0.z, 0.f);
          y[3] = (__bf16)fmaxf(a0.w - p0.w, 0.f);
          y[4] = (__bf16)fmaxf(a1.x - p1.x, 0.f);
          y[5] = (__bf16)fmaxf(a1.y - p1.y, 0.f);
          y[6] = (__bf16)fmaxf(a1.z - p1.z, 0.f);
          y[7] = (__bf16)fmaxf(a1.w - p1.w, 0.f);
          *(bf16x8*)(As + SWZP(r*1024 + lane*16, r)) = y;
        }
      }
      const int u0 = tid, u1 = tid + 512;
      const size_t gfo0 = (size_t)((u0 >> 6) * 16) * 512 + (u0 & 63) * 8;
      const size_t gfo1 = (size_t)((u1 >> 6) * 16) * 512 + (u1 & 63) * 8;
      {
        u16x8 s0 = *(const u16x8*)(Wfrag + gfo0);
        u16x8 s1 = *(const u16x8*)(Wfrag + gfo1);
        *(u16x8*)(B0 + u0*16) = s0;
        *(u16x8*)(B0 + u1*16) = s1;
      }
      u16x8 r0, r1;
      {
        r0 = *(const u16x8*)(Wfrag + 512 + gfo0);
        r1 = *(const u16x8*)(Wfrag + 512 + gfo1);
      }
      __syncthreads();
      for (int nt2 = 0; nt2 < 4; nt2++) {
        f32x4 acc[4][4] = {};
        for (int k0 = 0; k0 < 16; k0++) {
          const int q = nt2*16 + k0;
          char* Bcur = (q & 1) ? B1 : B0;
          char* Bnxt = (q & 1) ? B0 : B1;
          if (q < 63) {
            *(u16x8*)(Bnxt + u0*16) = r0;
            *(u16x8*)(Bnxt + u1*16) = r1;
          }
          if (q < 62) {
            const int q2 = q + 2;
            const size_t base = (size_t)((q2 >> 4) * 256 + (q2 & 15)) * 512;
            r0 = *(const u16x8*)(Wfrag + base + gfo0);
            r1 = *(const u16x8*)(Wfrag + base + gfo1);
          }
          bf16x8 af[4], bfr[4];
#pragma unroll
          for (int mf = 0; mf < 4; mf++) {
            const int row = wr*64 + mf*16 + l15;
            af[mf] = *(const bf16x8*)(As + SWZP(row*1024 + k0*64 + lhi*16, row));
          }
#pragma unroll
          for (int nf = 0; nf < 4; nf++)
            bfr[nf] = *(const bf16x8*)(Bcur + (wcn*4 + nf)*1024 + lane*16);
#pragma unroll
          for (int mf = 0; mf < 4; mf++)
#pragma unroll
            for (int nf = 0; nf < 4; nf++)
              acc[mf][nf] = __builtin_amdgcn_mfma_f32_16x16x32_bf16(
                  af[mf], bfr[nf], acc[mf][nf], 0, 0, 0);
          __syncthreads();
        }
#pragma unroll
        for (int isub = 0; isub < 2; isub++)
#pragma unroll
          for (int nf = 0; nf < 4; nf++) {
            f32x4 v0 = acc[isub*2][nf], v1 = acc[isub*2 + 1][nf];
            float mx = fmaxf(fmaxf(fmaxf(v0[0], v0[1]), fmaxf(v0[2], v0[3])),
                             fmaxf(fmaxf(v1[0], v1[1]), fmaxf(v1[2], v1[3])));
            mx = fmaxf(mx, __shfl_xor(mx, 16));
            mx = fmaxf(mx, __shfl_xor(mx, 32));
            if (lane < 16) {
              const int n = nt2*256 + wcn*64 + nf*16 + lane;
              const int i = mt*4 + wr*2 + isub;
              hcatB[(size_t)(g*32 + i)*1152 + 128 + n] =
                  bf16bits(fmaxf(mx + bp2[n], 0.f));
            }
          }
      }
    }
    grid.sync();

    // ---------- Phase 3: m1 (64x64 tile, 8 waves = 4 k-split x 2 n-split) ----
    {
      const int nt = bid & 15, mt = bid >> 4;
      const unsigned short* aSrc = hcatB + (size_t)(mt*64)*1152;
      const unsigned short* bSrc = Wm1t + (size_t)(nt*64)*1152;
      const int wk = w >> 1, wn = w & 1;
      u16x8 rg[4];
#pragma unroll
      for (int p = 0; p < 4; p++) {
        const int u = tid + p*512;
        const int isB = u >> 10, v = u & 1023;
        const int row = v >> 4, slot = v & 15;
        u16x8 val = *(const u16x8*)((isB ? bSrc : aSrc) + (size_t)row*1152 + slot*8);
        *(u16x8*)(smem + isB*16384 + SWZP(row*256 + slot*16, row)) = val;
      }
#pragma unroll
      for (int p = 0; p < 4; p++) {
        const int u = tid + p*512;
        const int isB = u >> 10, v = u & 1023;
        const int row = v >> 4, slot = v & 15;
        rg[p] = *(const u16x8*)((isB ? bSrc : aSrc) + (size_t)row*1152 + 128 + slot*8);
      }
      __syncthreads();
      f32x4 acc[4][2] = {};
      for (int c = 0; c < 9; c++) {
        const int cur = (c & 1) * 32768;
        const int nxt = 32768 - cur;
        if (c < 8) {
#pragma unroll
          for (int p = 0; p < 4; p++) {
            const int u = tid + p*512;
            const int isB = u >> 10, v = u & 1023;
            const int row = v >> 4, slot = v & 15;
            *(u16x8*)(smem + nxt + isB*16384 + SWZP(row*256 + slot*16, row)) = rg[p];
          }
        }
        if (c < 7) {
#pragma unroll
          for (int p = 0; p < 4; p++) {
            const int u = tid + p*512;
            const int isB = u >> 10, v = u & 1023;
            const int row = v >> 4, slot = v & 15;
            rg[p] = *(const u16x8*)((isB ? bSrc : aSrc) + (size_t)row*1152 +
                                    (c+2)*128 + slot*8);
          }
        }
        bf16x8 af[4], bf[2];
#pragma unroll
        for (int mf = 0; mf < 4; mf++) {
          const int row = mf*16 + l15;
          af[mf] = *(const bf16x8*)(smem + cur +
                                    SWZP(row*256 + wk*64 + lhi*16, row));
        }
#pragma unroll
        for (int nf = 0; nf < 2; nf++) {
          const int row = wn*32 + nf*16 + l15;
          bf[nf] = *(const bf16x8*)(smem + cur + 16384 +
                                    SWZP(row*256 + wk*64 + lhi*16, row));
        }
#pragma unroll
        for (int mf = 0; mf < 4; mf++)
#pragma unroll
          for (int nf = 0; nf < 2; nf++)
            acc[mf][nf] = __builtin_amdgcn_mfma_f32_16x16x32_bf16(
                af[mf], bf[nf], acc[mf][nf], 0, 0, 0);
        __syncthreads();
      }
      // reduce 4 k-wave partials per (mf, nfg) position
#pragma unroll
      for (int mf = 0; mf < 4; mf++)
#pragma unroll
        for (int nf = 0; nf < 2; nf++)
          *(f32x4*)(smem + (w*8 + mf*2 + nf)*1024 + lane*16) = acc[mf][nf];
      __syncthreads();
#pragma unroll
      for (int pi = 0; pi < 2; pi++) {
        const int p = w*2 + pi;          // 0..15
        const int mf = p >> 2, nfg = p & 3;
        f32x4 s = {0.f, 0.f, 0.f, 0.f};
#pragma unroll
        for (int wkk = 0; wkk < 4; wkk++) {
          const int src = (wkk*2 + (nfg >> 1))*8 + mf*2 + (nfg & 1);
          f32x4 q = *(const f32x4*)(smem + src*1024 + lane*16);
          s[0] += q[0]; s[1] += q[1]; s[2] += q[2]; s[3] += q[3];
        }
        const int col = nt*64 + nfg*16 + l15;
        const float bv = b_m1[col];
#pragma unroll
        for (int r = 0; r < 4; r++) {
          const int row = mt*64 + mf*16 + lhi*4 + r;
          midB[(size_t)row*1024 + col] = bf16bits(fmaxf(s[r] + bv, 0.f));
        }
      }
    }
    grid.sync();

    // ---------- Phase 4: m2 (64 active blocks, 8-way k-split) ----------
    if (bid < 64) {
      const int nt = bid & 1, mt = bid >> 1;   // 2 x 32
      const unsigned short* aSrc = midB  + (size_t)(mt*32)*1024;
      const unsigned short* bSrc = Wm2tB + (size_t)(nt*64)*1024;
      u16x8 rg[6];
#pragma unroll
      for (int p = 0; p < 6; p++) {
        const int u = tid + p*512;
        const int isB = (u >= 1024);
        const int v = isB ? (u - 1024) : u;
        const int row = v >> 5, slot = v & 31;
        u16x8 val = *(const u16x8*)((isB ? bSrc : aSrc) + (size_t)row*1024 + slot*8);
        *(u16x8*)(smem + isB*16384 + SWZP(row*512 + slot*16, row)) = val;
      }
#pragma unroll
      for (int p = 0; p < 6; p++) {
        const int u = tid + p*512;
        const int isB = (u >= 1024);
        const int v = isB ? (u - 1024) : u;
        const int row = v >> 5, slot = v & 31;
        rg[p] = *(const u16x8*)((isB ? bSrc : aSrc) + (size_t)row*1024 + 256 + slot*8);
      }
      __syncthreads();
      f32x4 acc[2][4] = {};
      for (int c = 0; c < 4; c++) {
        const int cur = (c & 1) * 49152;
        const int nxt = 49152 - cur;
        if (c < 3) {
#pragma unroll
          for (int p = 0; p < 6; p++) {
            const int u = tid + p*512;
            const int isB = (u >= 1024);
            const int v = isB ? (u - 1024) : u;
            const int row = v >> 5, slot = v & 31;
            *(u16x8*)(smem + nxt + isB*16384 + SWZP(row*512 + slot*16, row)) = rg[p];
          }
        }
        if (c < 2) {
#pragma unroll
          for (int p = 0; p < 6; p++) {
            const int u = tid + p*512;
            const int isB = (u >= 1024);
            const int v = isB ? (u - 1024) : u;
            const int row = v >> 5, slot = v & 31;
            rg[p] = *(const u16x8*)((isB ? bSrc : aSrc) + (size_t)row*1024 +
                                    (c+2)*256 + slot*8);
          }
        }
        bf16x8 af[2], bf[4];
#pragma unroll
        for (int mf = 0; mf < 2; mf++) {
          const int row = mf*16 + l15;
          af[mf] = *(const bf16x8*)(smem + cur +
                                    SWZP(row*512 + w*64 + lhi*16, row));
        }
#pragma unroll
        for (int nf = 0; nf < 4; nf++) {
          const int row = nf*16 + l15;
          bf[nf] = *(const bf16x8*)(smem + cur + 16384 +
                                    SWZP(row*512 + w*64 + lhi*16, row));
        }
#pragma unroll
        for (int mf = 0; mf < 2; mf++)
#pragma unroll
          for (int nf = 0; nf < 4; nf++)
            acc[mf][nf] = __builtin_amdgcn_mfma_f32_16x16x32_bf16(
                af[mf], bf[nf], acc[mf][nf], 0, 0, 0);
        __syncthreads();
      }
#pragma unroll
      for (int mf = 0; mf < 2; mf++)
#pragma unroll
        for (int nf = 0; nf < 4; nf++)
          *(f32x4*)(smem + (w*8 + mf*4 + nf)*1024 + lane*16) = acc[mf][nf];
      __syncthreads();
      {
        const int p = w;                 // 0..7
        const int mf = p >> 2, nf = p & 3;
        f32x4 s = {0.f, 0.f, 0.f, 0.f};
#pragma unroll
        for (int wv = 0; wv < 8; wv++) {
          f32x4 q = *(const f32x4*)(smem + (wv*8 + p)*1024 + lane*16);
          s[0] += q[0]; s[1] += q[1]; s[2] += q[2]; s[3] += q[3];
        }
        const int col = nt*64 + nf*16 + l15;
        const float bv = b_m2[col];
#pragma unroll
        for (int r = 0; r < 4; r++) {
          const int row = mt*32 + mf*16 + lhi*4 + r;
          h_dec[(size_t)row*128 + col] = fmaxf(s[r] + bv, 0.f);
        }
      }
    }
    grid.sync();
  }

  // ---------- final: h_dec -> out ----------
  {
    const int idx = bid * 512 + tid;   // 0..131071
    out[24576 + idx] = h_dec[idx];
  }
}

extern "C" void kernel_launch(void* const* d_in, const int* in_sizes, int n_in,
                              void* d_out, int out_size, void* d_ws, size_t ws_size,
                              hipStream_t stream) {
  const float* last_pos = (const float*)d_in[0];
  const float* lpr      = (const float*)d_in[1];
  const float* dh       = (const float*)d_in[2];
  const float* dc       = (const float*)d_in[3];
  const float* W_emb = (const float*)d_in[5];
  const float* b_emb = (const float*)d_in[6];
  const float* W_ih  = (const float*)d_in[7];
  const float* b_ih  = (const float*)d_in[8];
  const float* W_hh  = (const float*)d_in[9];
  const float* b_hh  = (const float*)d_in[10];
  const float* W_h2p = (const float*)d_in[11];
  const float* b_h2p = (const float*)d_in[12];
  const float* W_sp  = (const float*)d_in[13];
  const float* b_sp  = (const float*)d_in[14];
  const float* W_pp1 = (const float*)d_in[15];
  const float* b_pp1 = (const float*)d_in[16];
  const float* W_pp2 = (const float*)d_in[17];
  const float* b_pp2 = (const float*)d_in[18];
  const float* W_m1  = (const float*)d_in[19];
  const float* b_m1  = (const float*)d_in[20];
  const float* W_m2  = (const float*)d_in[21];
  const float* b_m2  = (const float*)d_in[22];

  float* ws    = (float*)d_ws;
  float* lp    = ws + OFF_LP;
  float* din   = ws + OFF_DIN;
  float* cst   = ws + OFF_C;
  float* h_dec = ws + OFF_HDEC;
  float* Wc    = ws + OFF_WC;
  float* bc    = ws + OFF_BC;
  float* PW    = ws + OFF_PW;
  float* Aa    = ws + OFF_AA;
  unsigned short* Wp2t  = (unsigned short*)(ws + OFF_WP2T);
  unsigned short* Wm1t  = (unsigned short*)(ws + OFF_WM1T);
  unsigned short* hcatB = (unsigned short*)(ws + OFF_HCATB);
  unsigned short* Wm2tB = (unsigned short*)(ws + OFF_WM2TB);
  unsigned short* midB  = (unsigned short*)(ws + OFF_MIDB);
  float* Wiht  = ws + OFF_WIHT;
  float* Whht  = ws + OFF_WHHT;
  unsigned short* Wfrag = (unsigned short*)(ws + OFF_WFRAG);
  float* out   = (float*)d_out;
  const float* W1b = W_pp1 + 64*512;

  k_setup<<<512, 256, 0, stream>>>(last_pos, lpr, dh, dc, W_emb, b_emb, lp, din, h_dec, cst);
  k_wc<<<2, 256, 0, stream>>>(W_sp, b_sp, W_pp1, b_pp1, Wc, bc);
  { dim3 gt(32, 16); k_tcvt<<<gt, 256, 0, stream>>>(W_pp2, Wp2t, 512, 1024); }
  { dim3 gt(32, 36); k_tcvt<<<gt, 256, 0, stream>>>(W_m1, Wm1t, 1152, 1024); }
  { dim3 gt(4, 32);  k_tcvt<<<gt, 256, 0, stream>>>(W_m2, Wm2tB, 1024, 128); }
  { dim3 gt(2, 16);  k_t32<<<gt, 256, 0, stream>>>(W_ih, Wiht, 512, 64); }
  { dim3 gt(4, 16);  k_t32<<<gt, 256, 0, stream>>>(W_hh, Whht, 512, 128); }
  k_frag<<<256, 256, 0, stream>>>(Wp2t, Wfrag);

  void* args[] = {
    (void*)&din, (void*)&cst, (void*)&h_dec, (void*)&hcatB,
    (void*)&lp, (void*)&out,
    (void*)&Wiht, (void*)&b_ih, (void*)&Whht, (void*)&b_hh,
    (void*)&W_h2p, (void*)&b_h2p, (void*)&W_emb, (void*)&b_emb,
    (void*)&W1b, (void*)&Wc, (void*)&bc,
    (void*)&PW, (void*)&Aa,
    (void*)&Wfrag, (void*)&b_pp2,
    (void*)&Wm1t, (void*)&b_m1, (void*)&midB,
    (void*)&Wm2tB, (void*)&b_m2
  };
  hipLaunchCooperativeKernel((void*)k_mega, dim3(256), dim3(512), args, 0, stream);
}

// Round 15
// 966.303 us; speedup vs baseline: 2.4112x; 2.4112x over previous
//
#include <hip/hip_runtime.h>
#include <math.h>

#define T_SEQ 12
// B=1024, NG=32, G=32, E=64, H=128, PP=512, BOT=1024, MLPD=1024

typedef __bf16 bf16x8 __attribute__((ext_vector_type(8)));
typedef float f32x4 __attribute__((ext_vector_type(4)));
typedef unsigned short u16x8 __attribute__((ext_vector_type(8)));

static __device__ __forceinline__ unsigned short bf16bits(float x) {
  return __builtin_bit_cast(unsigned short, (__bf16)x);
}

// Workspace layout (float offsets)
enum : int {
  OFF_LP    = 0,        // [1024,2]
  OFF_DIN   = 2048,     // [1024,64]
  OFF_C     = 198656,   // [1024,128]
  OFF_HDEC  = 329728,   // [1024,128]
  OFF_WC    = 460800,   // [2,512]
  OFF_BC    = 461824,   // [512]
  OFF_PW    = 462336,   // [1024,512]
  OFF_AA    = 986624,   // [1024,512]
  OFF_WP2T  = 1510912,  // [1024,512] bf16
  OFF_WM1T  = 1773056,  // [1024,1152] bf16
  OFF_HCATB = 2362880,  // [1024,1152] bf16 (h | pool)
  OFF_WM2TB = 2952704,  // [128,1024] bf16
  OFF_MIDB  = 3018240,  // [1024,1024] bf16
  OFF_WIHT  = 3542528,  // [64,512] f32 (W_ih^T)
  OFF_WHHT  = 3575296,  // [128,512] f32 (W_hh^T)
  OFF_WFRAG = 3640832   // [1024 frags][64 lanes][8] bf16 = 131072 floats
};                      // end 3771904 floats = 15.1 MB

// XOR swizzle: permute 16B slots within each 128B group by row&7
#define SWZP(byte, row) ((byte) ^ (((row) & 7) << 4))

__global__ __launch_bounds__(256) void k_setup(
    const float* __restrict__ last_pos, const float* __restrict__ lpr,
    const float* __restrict__ dh, const float* __restrict__ dc,
    const float* __restrict__ W_emb, const float* __restrict__ b_emb,
    float* __restrict__ lp, float* __restrict__ din,
    float* __restrict__ h_dec, float* __restrict__ c) {
  int idx = blockIdx.x * 256 + threadIdx.x;  // 0..131071
  if (idx < 2048) lp[idx] = last_pos[idx];
  h_dec[idx] = dh[idx];
  c[idx] = dc[idx];
  if (idx < 65536) {
    int b = idx >> 6, e = idx & 63;
    din[idx] = lpr[b*2] * W_emb[e] + lpr[b*2+1] * W_emb[64+e] + b_emb[e];
  }
}

__global__ __launch_bounds__(256) void k_wc(
    const float* __restrict__ W_sp, const float* __restrict__ b_sp,
    const float* __restrict__ W_pp1, const float* __restrict__ b_pp1,
    float* __restrict__ Wc, float* __restrict__ bc) {
  int n = blockIdx.x * 256 + threadIdx.x;
  if (n >= 512) return;
  float a0 = 0.f, a1 = 0.f, ab = 0.f;
#pragma unroll 8
  for (int k = 0; k < 64; k++) {
    float w = W_pp1[k*512 + n];
    a0 += W_sp[k] * w;
    a1 += W_sp[64+k] * w;
    ab += b_sp[k] * w;
  }
  Wc[n] = a0; Wc[512+n] = a1; bc[n] = ab + b_pp1[n];
}

// Transpose + convert fp32 [R][C] -> bf16 [C][R]
__global__ __launch_bounds__(256) void k_tcvt(
    const float* __restrict__ src, unsigned short* __restrict__ dst,
    int R, int C) {
  __shared__ float t[32][33];
  const int bx = blockIdx.x * 32, by = blockIdx.y * 32;
  const int tx = threadIdx.x & 31, ty = threadIdx.x >> 5;
#pragma unroll
  for (int i = 0; i < 32; i += 8) t[ty+i][tx] = src[(size_t)(by+ty+i)*C + bx+tx];
  __syncthreads();
#pragma unroll
  for (int i = 0; i < 32; i += 8)
    dst[(size_t)(bx+ty+i)*R + by+tx] = bf16bits(t[tx][ty+i]);
}

// Transpose fp32 [R][C] -> fp32 [C][R]
__global__ __launch_bounds__(256) void k_t32(
    const float* __restrict__ src, float* __restrict__ dst, int R, int C) {
  __shared__ float t[32][33];
  const int bx = blockIdx.x * 32, by = blockIdx.y * 32;
  const int tx = threadIdx.x & 31, ty = threadIdx.x >> 5;
#pragma unroll
  for (int i = 0; i < 32; i += 8) t[ty+i][tx] = src[(size_t)(by+ty+i)*C + bx+tx];
  __syncthreads();
#pragma unroll
  for (int i = 0; i < 32; i += 8)
    dst[(size_t)(bx+ty+i)*R + by+tx] = t[tx][ty+i];
}

// Re-arrange Wp2t [1024n][512k] into MFMA B-fragment order:
// Wfrag[fid][lane][8], fid = nbb*16 + kstep.
__global__ __launch_bounds__(256) void k_frag(
    const unsigned short* __restrict__ Wp2t, unsigned short* __restrict__ Wfrag) {
  const int tid = blockIdx.x * 256 + threadIdx.x;  // 0..65535
  const int fid = tid >> 6, l = tid & 63;
  const int nbb = fid >> 4, ks = fid & 15;
  u16x8 v = *(const u16x8*)(Wp2t + (size_t)(nbb*16 + (l & 15))*512 +
                            ks*32 + (l >> 4)*8);
  *(u16x8*)(Wfrag + (size_t)tid*8) = v;
}

// Fused LSTM + h2pos + pool-A-prep: 4 batch rows/block, 512 threads, 256 blocks.
__global__ __launch_bounds__(512) void k_step1(
    float* __restrict__ din, const float* __restrict__ h_dec,
    float* __restrict__ cst, unsigned short* __restrict__ hcatB,
    float* __restrict__ lp, float* __restrict__ pred,
    const float* __restrict__ Wiht, const float* __restrict__ b_ih,
    const float* __restrict__ Whht, const float* __restrict__ b_hh,
    const float* __restrict__ W_h2p, const float* __restrict__ b_h2p,
    const float* __restrict__ W_emb, const float* __restrict__ b_emb,
    const float* __restrict__ W1b, const float* __restrict__ Wc,
    const float* __restrict__ bc,
    float* __restrict__ PW, float* __restrict__ Aa, int t) {
  const int b0 = blockIdx.x * 4;
  const int tid = threadIdx.x;
  __shared__ float xh[4*192];
  __shared__ float gl[4*512];
  __shared__ float hbuf[4*128];
  __shared__ float relS[8], curS[8];

  for (int i = tid; i < 768; i += 512) {
    int r = i / 192, k = i - r*192;
    xh[i] = (k < 64) ? din[(b0+r)*64 + k] : h_dec[(b0+r)*128 + k - 64];
  }
  __syncthreads();
  {
    const int n = tid;
    float bias = b_ih[n] + b_hh[n];
    float acc[4] = {bias, bias, bias, bias};
#pragma unroll 8
    for (int k = 0; k < 64; k++) {
      float wv = Wiht[k*512 + n];
#pragma unroll
      for (int r = 0; r < 4; r++) acc[r] += xh[r*192 + k] * wv;
    }
#pragma unroll 8
    for (int k = 0; k < 128; k++) {
      float wv = Whht[k*512 + n];
#pragma unroll
      for (int r = 0; r < 4; r++) acc[r] += xh[r*192 + 64 + k] * wv;
    }
#pragma unroll
    for (int r = 0; r < 4; r++) gl[r*512 + n] = acc[r];
  }
  __syncthreads();
  {
    int r = tid >> 7, hh = tid & 127;
    float ig = gl[r*512 + hh],       fg = gl[r*512 + 128 + hh];
    float gg = gl[r*512 + 256 + hh], og = gl[r*512 + 384 + hh];
    ig = 1.f/(1.f+expf(-ig)); fg = 1.f/(1.f+expf(-fg));
    gg = tanhf(gg);           og = 1.f/(1.f+expf(-og));
    int row = b0 + r;
    float c2 = fg * cst[row*128 + hh] + ig * gg;
    float h2 = og * tanhf(c2);
    cst[row*128 + hh] = c2;
    hbuf[r*128 + hh] = h2;
    hcatB[(size_t)row*1152 + hh] = bf16bits(h2);
  }
  __syncthreads();
  if (tid < 128) {
    int r = tid >> 5, col = (tid >> 4) & 1, l16 = tid & 15;
    float s = 0.f;
    for (int k = l16; k < 128; k += 16) s += hbuf[r*128 + k] * W_h2p[k*2 + col];
#pragma unroll
    for (int off = 8; off > 0; off >>= 1) s += __shfl_xor(s, off);
    if (l16 == 0) {
      float rel = s + b_h2p[col];
      float old = lp[(b0+r)*2 + col];
      relS[r*2 + col] = rel;
      curS[r*2 + col] = old + rel;
      lp[(b0+r)*2 + col] = old + rel;
      pred[t*2048 + (b0+r)*2 + col] = rel;
    }
  }
  __syncthreads();
  if (tid < 256) {
    int r = tid >> 6, e = tid & 63;
    din[(b0+r)*64 + e] = relS[r*2]*W_emb[e] + relS[r*2+1]*W_emb[64+e] + b_emb[e];
  }
  {
    const int n = tid;
    float acc[4] = {0.f, 0.f, 0.f, 0.f};
#pragma unroll 4
    for (int k = 0; k < 128; k++) {
      float wv = W1b[k*512 + n];
#pragma unroll
      for (int r = 0; r < 4; r++) acc[r] += hbuf[r*128 + k] * wv;
    }
    float wc0 = Wc[n], wc1 = Wc[512+n], bcv = bc[n];
#pragma unroll
    for (int r = 0; r < 4; r++) {
      float pw = curS[r*2]*wc0 + curS[r*2+1]*wc1;
      PW[(size_t)(b0+r)*512 + n] = pw;
      Aa[(size_t)(b0+r)*512 + n] = acc[r] + pw + bcv;
    }
  }
}

// --- Pool GEMM v8 (R10-exact): A-resident 128KB LDS + B staged in
// MFMA-fragment layout, double-buffered (2x16KB). One __syncthreads per
// k-step. Best measured configuration (44.8us).
__global__ __launch_bounds__(512) void k_pool8(
    const float* __restrict__ Aa, const float* __restrict__ PW,
    const unsigned short* __restrict__ Wfrag, const float* __restrict__ bp2,
    unsigned short* __restrict__ hcatB) {
  const int bid = blockIdx.x;
  const int mt = (bid >> 3) & 7;
  const int g  = (bid & 7) + ((bid >> 6) << 3);
  const int tid = threadIdx.x, lane = tid & 63, w = tid >> 6;
  const int wr = w >> 2, wc = w & 3;     // 2m x 4n waves, wave tile 64m x 64n
  const int l15 = lane & 15, lhi = lane >> 4;
  __shared__ __align__(128) char lds[163840];
  char* As = lds;                 // [128 rows][1024B] swizzled
  char* B0 = lds + 131072;        // chunk buffer 0 [16 nb][1024B]
  char* B1 = lds + 131072 + 16384;

  // Build A tile (rows m = ii*32 + j, i = mt*4+ii): conflict-free wave rows.
  {
    const int ke = lane * 8;
#pragma unroll 4
    for (int rr = 0; rr < 16; rr++) {
      const int r = rr * 8 + w;
      const int j = r & 31, ii = r >> 5;
      const float* aRow = Aa + (size_t)(g*32 + j)*512 + ke;
      const float* pRow = PW + (size_t)(g*32 + mt*4 + ii)*512 + ke;
      float4 a0 = *(const float4*)aRow;
      float4 a1 = *(const float4*)(aRow + 4);
      float4 p0 = *(const float4*)pRow;
      float4 p1 = *(const float4*)(pRow + 4);
      bf16x8 y;
      y[0] = (__bf16)fmaxf(a0.x - p0.x, 0.f);
      y[1] = (__bf16)fmaxf(a0.y - p0.y, 0.f);
      y[2] = (__bf16)fmaxf(a0.z - p0.z, 0.f);
      y[3] = (__bf16)fmaxf(a0.w - p0.w, 0.f);
      y[4] = (__bf16)fmaxf(a1.x - p1.x, 0.f);
      y[5] = (__bf16)fmaxf(a1.y - p1.y, 0.f);
      y[6] = (__bf16)fmaxf(a1.z - p1.z, 0.f);
      y[7] = (__bf16)fmaxf(a1.w - p1.w, 0.f);
      *(bf16x8*)(As + SWZP(r*1024 + lane*16, r)) = y;
    }
  }

  const int u0 = tid, u1 = tid + 512;
  const size_t gfo0 = (size_t)((u0 >> 6) * 16) * 512 + (u0 & 63) * 8;
  const size_t gfo1 = (size_t)((u1 >> 6) * 16) * 512 + (u1 & 63) * 8;

  // prologue: chunk 0 -> B0; chunk 1 -> regs
  {
    u16x8 s0 = *(const u16x8*)(Wfrag + gfo0);
    u16x8 s1 = *(const u16x8*)(Wfrag + gfo1);
    *(u16x8*)(B0 + u0*16) = s0;
    *(u16x8*)(B0 + u1*16) = s1;
  }
  u16x8 r0, r1;
  {
    const size_t base = (size_t)512;  // q=1
    r0 = *(const u16x8*)(Wfrag + base + gfo0);
    r1 = *(const u16x8*)(Wfrag + base + gfo1);
  }
  __syncthreads();

  for (int nt = 0; nt < 4; nt++) {
    f32x4 acc[4][4] = {};
    for (int k0 = 0; k0 < 16; k0++) {
      const int q = nt*16 + k0;
      char* Bcur = (q & 1) ? B1 : B0;
      char* Bnxt = (q & 1) ? B0 : B1;
      if (q < 63) {  // write chunk q+1 (loaded at iter q-1 / prologue)
        *(u16x8*)(Bnxt + u0*16) = r0;
        *(u16x8*)(Bnxt + u1*16) = r1;
      }
      if (q < 62) {  // issue loads for chunk q+2
        const int q2 = q + 2;
        const size_t base = (size_t)((q2 >> 4) * 256 + (q2 & 15)) * 512;
        r0 = *(const u16x8*)(Wfrag + base + gfo0);
        r1 = *(const u16x8*)(Wfrag + base + gfo1);
      }
      bf16x8 af[4], bfr[4];
#pragma unroll
      for (int mf = 0; mf < 4; mf++) {
        const int row = wr*64 + mf*16 + l15;
        af[mf] = *(const bf16x8*)(As + SWZP(row*1024 + k0*64 + lhi*16, row));
      }
#pragma unroll
      for (int nf = 0; nf < 4; nf++)
        bfr[nf] = *(const bf16x8*)(Bcur + (wc*4 + nf)*1024 + lane*16);
#pragma unroll
      for (int mf = 0; mf < 4; mf++)
#pragma unroll
        for (int nf = 0; nf < 4; nf++)
          acc[mf][nf] = __builtin_amdgcn_mfma_f32_16x16x32_bf16(
              af[mf], bfr[nf], acc[mf][nf], 0, 0, 0);
      __syncthreads();
    }
    // epilogue: max over j, bias, relu -> hcatB pool columns
#pragma unroll
    for (int isub = 0; isub < 2; isub++)
#pragma unroll
      for (int nf = 0; nf < 4; nf++) {
        f32x4 v0 = acc[isub*2][nf], v1 = acc[isub*2 + 1][nf];
        float mx = fmaxf(fmaxf(fmaxf(v0[0], v0[1]), fmaxf(v0[2], v0[3])),
                         fmaxf(fmaxf(v1[0], v1[1]), fmaxf(v1[2], v1[3])));
        mx = fmaxf(mx, __shfl_xor(mx, 16));
        mx = fmaxf(mx, __shfl_xor(mx, 32));
        if (lane < 16) {
          const int n = nt*256 + wc*64 + nf*16 + lane;
          const int i = mt*4 + wr*2 + isub;
          hcatB[(size_t)(g*32 + i)*1152 + 128 + n] =
              bf16bits(fmaxf(mx + bp2[n], 0.f));
        }
      }
  }
}

// mid = relu(hcatB @ Wm1t^T + b_m1) -> bf16 midB.
// K-split-wave GEMM (R11): grid (16,16), 256 thr, 4 waves k-split.
__global__ __launch_bounds__(256) void k_m1k(
    const unsigned short* __restrict__ A, const unsigned short* __restrict__ Bw,
    const float* __restrict__ bias, unsigned short* __restrict__ outB) {
  const int nt = blockIdx.x, mt = blockIdx.y;
  const int tid = threadIdx.x, lane = tid & 63, w = tid >> 6;
  const int l15 = lane & 15, lhi = lane >> 4;
  __shared__ __align__(128) char lds[65536];  // buf b: A @ b*32768, B @ +16384
  const unsigned short* aSrc = A  + (size_t)(mt*64)*1152;
  const unsigned short* bSrc = Bw + (size_t)(nt*64)*1152;

  u16x8 rg[8];
#pragma unroll
  for (int p = 0; p < 8; p++) {
    const int u = tid + p*256;
    const int isB = u >> 10, v = u & 1023;
    const int row = v >> 4, slot = v & 15;
    u16x8 val = *(const u16x8*)((isB ? bSrc : aSrc) + (size_t)row*1152 + slot*8);
    *(u16x8*)(lds + isB*16384 + SWZP(row*256 + slot*16, row)) = val;
  }
#pragma unroll
  for (int p = 0; p < 8; p++) {
    const int u = tid + p*256;
    const int isB = u >> 10, v = u & 1023;
    const int row = v >> 4, slot = v & 15;
    rg[p] = *(const u16x8*)((isB ? bSrc : aSrc) + (size_t)row*1152 + 128 + slot*8);
  }
  __syncthreads();

  f32x4 acc[4][4] = {};
  for (int c = 0; c < 9; c++) {
    const int cur = (c & 1) * 32768;
    const int nxt = 32768 - cur;
    if (c < 8) {
#pragma unroll
      for (int p = 0; p < 8; p++) {
        const int u = tid + p*256;
        const int isB = u >> 10, v = u & 1023;
        const int row = v >> 4, slot = v & 15;
        *(u16x8*)(lds + nxt + isB*16384 + SWZP(row*256 + slot*16, row)) = rg[p];
      }
    }
    if (c < 7) {
#pragma unroll
      for (int p = 0; p < 8; p++) {
        const int u = tid + p*256;
        const int isB = u >> 10, v = u & 1023;
        const int row = v >> 4, slot = v & 15;
        rg[p] = *(const u16x8*)((isB ? bSrc : aSrc) + (size_t)row*1152 +
                                (c+2)*128 + slot*8);
      }
    }
    bf16x8 af[4], bf[4];
#pragma unroll
    for (int mf = 0; mf < 4; mf++) {
      const int row = mf*16 + l15;
      af[mf] = *(const bf16x8*)(lds + cur + SWZP(row*256 + w*64 + lhi*16, row));
    }
#pragma unroll
    for (int nf = 0; nf < 4; nf++) {
      const int row = nf*16 + l15;
      bf[nf] = *(const bf16x8*)(lds + cur + 16384 +
                                SWZP(row*256 + w*64 + lhi*16, row));
    }
#pragma unroll
    for (int mf = 0; mf < 4; mf++)
#pragma unroll
      for (int nf = 0; nf < 4; nf++)
        acc[mf][nf] = __builtin_amdgcn_mfma_f32_16x16x32_bf16(
            af[mf], bf[nf], acc[mf][nf], 0, 0, 0);
    __syncthreads();
  }

#pragma unroll
  for (int mf = 0; mf < 4; mf++)
#pragma unroll
    for (int nf = 0; nf < 4; nf++)
      *(f32x4*)(lds + w*16384 + (mf*4 + nf)*1024 + lane*16) = acc[mf][nf];
  __syncthreads();
#pragma unroll
  for (int pi = 0; pi < 4; pi++) {
    const int p = w*4 + pi;
    f32x4 s = *(const f32x4*)(lds + p*1024 + lane*16);
#pragma unroll
    for (int wv = 1; wv < 4; wv++) {
      f32x4 q = *(const f32x4*)(lds + wv*16384 + p*1024 + lane*16);
      s[0] += q[0]; s[1] += q[1]; s[2] += q[2]; s[3] += q[3];
    }
    const int col = nt*64 + (p & 3)*16 + l15;
    const float bv = bias[col];
#pragma unroll
    for (int r = 0; r < 4; r++) {
      const int row = mt*64 + (p >> 2)*16 + lhi*4 + r;
      outB[(size_t)row*1024 + col] = bf16bits(fmaxf(s[r] + bv, 0.f));
    }
  }
}

// h_dec = relu(midB @ Wm2tB^T + b_m2) fp32. K-split-wave (R11).
// At t==T_SEQ-1 also writes out[24576 + row*128 + col] (folds k_hfin).
__global__ __launch_bounds__(256) void k_m2k(
    const unsigned short* __restrict__ A, const unsigned short* __restrict__ Bw,
    const float* __restrict__ bias, float* __restrict__ hd,
    float* __restrict__ out, int last) {
  const int nt = blockIdx.x, mt = blockIdx.y;
  const int tid = threadIdx.x, lane = tid & 63, w = tid >> 6;
  const int l15 = lane & 15, lhi = lane >> 4;
  __shared__ __align__(128) char lds[49152];  // buf b @ b*24576: A 8KB, B 16KB
  const unsigned short* aSrc = A  + (size_t)(mt*32)*1024;
  const unsigned short* bSrc = Bw + (size_t)(nt*64)*1024;

  u16x8 rg[6];
#pragma unroll
  for (int p = 0; p < 6; p++) {
    const int u = tid + p*256;
    const int isB = (u >= 512);
    const int v = isB ? (u - 512) : u;
    const int row = v >> 4, slot = v & 15;
    u16x8 val = *(const u16x8*)((isB ? bSrc : aSrc) + (size_t)row*1024 + slot*8);
    *(u16x8*)(lds + isB*8192 + SWZP(row*256 + slot*16, row)) = val;
  }
#pragma unroll
  for (int p = 0; p < 6; p++) {
    const int u = tid + p*256;
    const int isB = (u >= 512);
    const int v = isB ? (u - 512) : u;
    const int row = v >> 4, slot = v & 15;
    rg[p] = *(const u16x8*)((isB ? bSrc : aSrc) + (size_t)row*1024 + 128 + slot*8);
  }
  __syncthreads();

  f32x4 acc[2][4] = {};
  for (int c = 0; c < 8; c++) {
    const int cur = (c & 1) * 24576;
    const int nxt = 24576 - cur;
    if (c < 7) {
#pragma unroll
      for (int p = 0; p < 6; p++) {
        const int u = tid + p*256;
        const int isB = (u >= 512);
        const int v = isB ? (u - 512) : u;
        const int row = v >> 4, slot = v & 15;
        *(u16x8*)(lds + nxt + isB*8192 + SWZP(row*256 + slot*16, row)) = rg[p];
      }
    }
    if (c < 6) {
#pragma unroll
      for (int p = 0; p < 6; p++) {
        const int u = tid + p*256;
        const int isB = (u >= 512);
        const int v = isB ? (u - 512) : u;
        const int row = v >> 4, slot = v & 15;
        rg[p] = *(const u16x8*)((isB ? bSrc : aSrc) + (size_t)row*1024 +
                                (c+2)*128 + slot*8);
      }
    }
    bf16x8 af[2], bf[4];
#pragma unroll
    for (int mf = 0; mf < 2; mf++) {
      const int row = mf*16 + l15;
      af[mf] = *(const bf16x8*)(lds + cur + SWZP(row*256 + w*64 + lhi*16, row));
    }
#pragma unroll
    for (int nf = 0; nf < 4; nf++) {
      const int row = nf*16 + l15;
      bf[nf] = *(const bf16x8*)(lds + cur + 8192 +
                                SWZP(row*256 + w*64 + lhi*16, row));
    }
#pragma unroll
    for (int mf = 0; mf < 2; mf++)
#pragma unroll
      for (int nf = 0; nf < 4; nf++)
        acc[mf][nf] = __builtin_amdgcn_mfma_f32_16x16x32_bf16(
            af[mf], bf[nf], acc[mf][nf], 0, 0, 0);
    __syncthreads();
  }

#pragma unroll
  for (int mf = 0; mf < 2; mf++)
#pragma unroll
    for (int nf = 0; nf < 4; nf++)
      *(f32x4*)(lds + w*8192 + (mf*4 + nf)*1024 + lane*16) = acc[mf][nf];
  __syncthreads();
#pragma unroll
  for (int pi = 0; pi < 2; pi++) {
    const int p = w*2 + pi;
    f32x4 s = *(const f32x4*)(lds + p*1024 + lane*16);
#pragma unroll
    for (int wv = 1; wv < 4; wv++) {
      f32x4 q = *(const f32x4*)(lds + wv*8192 + p*1024 + lane*16);
      s[0] += q[0]; s[1] += q[1]; s[2] += q[2]; s[3] += q[3];
    }
    const int col = nt*64 + (p & 3)*16 + l15;
    const float bv = bias[col];
#pragma unroll
    for (int r = 0; r < 4; r++) {
      const int row = mt*32 + (p >> 2)*16 + lhi*4 + r;
      float v = fmaxf(s[r] + bv, 0.f);
      hd[(size_t)row*128 + col] = v;
      if (last) out[24576 + (size_t)row*128 + col] = v;
    }
  }
}

extern "C" void kernel_launch(void* const* d_in, const int* in_sizes, int n_in,
                              void* d_out, int out_size, void* d_ws, size_t ws_size,
                              hipStream_t stream) {
  const float* last_pos = (const float*)d_in[0];
  const float* lpr      = (const float*)d_in[1];
  const float* dh       = (const float*)d_in[2];
  const float* dc       = (const float*)d_in[3];
  const float* W_emb = (const float*)d_in[5];
  const float* b_emb = (const float*)d_in[6];
  const float* W_ih  = (const float*)d_in[7];
  const float* b_ih  = (const float*)d_in[8];
  const float* W_hh  = (const float*)d_in[9];
  const float* b_hh  = (const float*)d_in[10];
  const float* W_h2p = (const float*)d_in[11];
  const float* b_h2p = (const float*)d_in[12];
  const float* W_sp  = (const float*)d_in[13];
  const float* b_sp  = (const float*)d_in[14];
  const float* W_pp1 = (const float*)d_in[15];
  const float* b_pp1 = (const float*)d_in[16];
  const float* W_pp2 = (const float*)d_in[17];
  const float* b_pp2 = (const float*)d_in[18];
  const float* W_m1  = (const float*)d_in[19];
  const float* b_m1  = (const float*)d_in[20];
  const float* W_m2  = (const float*)d_in[21];
  const float* b_m2  = (const float*)d_in[22];

  float* ws    = (float*)d_ws;
  float* lp    = ws + OFF_LP;
  float* din   = ws + OFF_DIN;
  float* cst   = ws + OFF_C;
  float* h_dec = ws + OFF_HDEC;
  float* Wc    = ws + OFF_WC;
  float* bc    = ws + OFF_BC;
  float* PW    = ws + OFF_PW;
  float* Aa    = ws + OFF_AA;
  unsigned short* Wp2t  = (unsigned short*)(ws + OFF_WP2T);
  unsigned short* Wm1t  = (unsigned short*)(ws + OFF_WM1T);
  unsigned short* hcatB = (unsigned short*)(ws + OFF_HCATB);
  unsigned short* Wm2tB = (unsigned short*)(ws + OFF_WM2TB);
  unsigned short* midB  = (unsigned short*)(ws + OFF_MIDB);
  float* Wiht  = ws + OFF_WIHT;
  float* Whht  = ws + OFF_WHHT;
  unsigned short* Wfrag = (unsigned short*)(ws + OFF_WFRAG);
  float* out   = (float*)d_out;

  k_setup<<<512, 256, 0, stream>>>(last_pos, lpr, dh, dc, W_emb, b_emb, lp, din, h_dec, cst);
  k_wc<<<2, 256, 0, stream>>>(W_sp, b_sp, W_pp1, b_pp1, Wc, bc);
  { dim3 gt(32, 16); k_tcvt<<<gt, 256, 0, stream>>>(W_pp2, Wp2t, 512, 1024); }
  { dim3 gt(32, 36); k_tcvt<<<gt, 256, 0, stream>>>(W_m1, Wm1t, 1152, 1024); }
  { dim3 gt(4, 32);  k_tcvt<<<gt, 256, 0, stream>>>(W_m2, Wm2tB, 1024, 128); }
  { dim3 gt(2, 16);  k_t32<<<gt, 256, 0, stream>>>(W_ih, Wiht, 512, 64); }
  { dim3 gt(4, 16);  k_t32<<<gt, 256, 0, stream>>>(W_hh, Whht, 512, 128); }
  k_frag<<<256, 256, 0, stream>>>(Wp2t, Wfrag);

  for (int t = 0; t < T_SEQ; t++) {
    k_step1<<<256, 512, 0, stream>>>(din, h_dec, cst, hcatB, lp, out,
                                     Wiht, b_ih, Whht, b_hh, W_h2p, b_h2p,
                                     W_emb, b_emb, W_pp1 + 64*512, Wc, bc,
                                     PW, Aa, t);
    k_pool8<<<256, 512, 0, stream>>>(Aa, PW, Wfrag, b_pp2, hcatB);
    { dim3 gm(16, 16); k_m1k<<<gm, 256, 0, stream>>>(hcatB, Wm1t, b_m1, midB); }
    { dim3 gm(2, 32);  k_m2k<<<gm, 256, 0, stream>>>(midB, Wm2tB, b_m2, h_dec,
                                                     out, t == T_SEQ-1); }
  }
}